// Round 8
// baseline (5106.770 us; speedup 1.0000x reference)
//
#include <hip/hip_runtime.h>

// ESN recurrence on MI355X: h_t = tanh(x_t @ W_in^T + h_{t-1} @ W_res^T)
// B=64, T=512, I=128, H=2048. Persistent cooperative kernel, 256 WGs (1/CU).
// WG (bg,j): batches [bg*16, bg*16+16), rows [j*32, j*32+32).
// W_res slice fp16 in LDS (resident); W_in slice fp16 hi+lo in LDS.
// R8: in-band tags (R7 idea), mechanically de-risked:
//  - h element = dword (tag16<<16)|fp16; dword loads single-copy atomic =>
//    tag==t proves step-t data. No fences, no tag array, no publish barrier.
//  - k processed in 4 chunks x 16 u64, double-buffered => ~64 VGPRs of h in
//    flight (R7's q[64]=128+ VGPRs likely broke the coop launch).
//  - ht0 aliased onto d_out (0.5 MB) => d_ws use = 0.5 MB (proven R1-R6 size).
//    Safe: entering t=511 (overwrites ht0 with final fp32) requires tag-511
//    from all same-bg peers, published only after their t=510 ht0 reads done;
//    cross-bg regions are batch-disjoint addresses.
//  - s_sleep only in the retry path.
// Deadlock/overwrite safety (unchanged transitive argument): seeing ANY of
// peer Q's tag-t data => Q finished step t-1 => Q read all tag-(t-1) data =>
// overwriting that buffer (tag t+1 writes) is safe; a WG stuck at step t
// withholds its own tag-(t+1), stalling any would-be overwriter of its inputs.

#define B_ 64
#define T_ 512
#define I_ 128
#define H_ 2048
#define NWG 256
#define ROWS 32          // output rows per WG
#define BATS 16          // batches per WG
#define WPAD 2056        // 2048 + 8 halves row pad
#define IPAD 136         // 128 + 8 halves row pad
#define PPAD 33          // partial row pad (break 32-bank stride)

typedef _Float16 f16;
typedef f16 f16x8 __attribute__((ext_vector_type(8)));
typedef float f32x4 __attribute__((ext_vector_type(4)));
typedef unsigned long long u64;
typedef unsigned int u32;

// LDS layout (bytes):
//   Wres  : ROWS*WPAD*2           = 131584
//   Win_hi: ROWS*IPAD*2           =   8704
//   Win_lo: ROWS*IPAD*2           =   8704
//   part  : 4*BATS*PPAD*4         =   8448
#define LDS_WRES   0
#define LDS_WINHI  131584
#define LDS_WINLO  (131584 + 8704)
#define LDS_PART   (131584 + 17408)
#define LDS_TOTAL  (131584 + 17408 + 8448)

__device__ __forceinline__ void load_chunk(u64* q, const u64* cp)
{
    #pragma unroll
    for (int i = 0; i < 4; i++)
        #pragma unroll
        for (int e = 0; e < 4; e++)
            q[i * 4 + e] = __hip_atomic_load(cp + i * 16 + e, __ATOMIC_RELAXED,
                                             __HIP_MEMORY_SCOPE_AGENT);
}

__device__ __forceinline__ void check_retry(u64* q, const u64* cp, u64 E)
{
    const u64 M = 0xFFFF0000FFFF0000ULL;
    for (;;) {
        u64 bad = 0;
        #pragma unroll
        for (int i = 0; i < 16; i++) bad |= (q[i] & M) ^ E;
        if (__all(bad == 0)) break;
        if (bad) {                      // only stale lanes re-load (exec-masked)
            __builtin_amdgcn_s_sleep(1);
            load_chunk(q, cp);
        }
    }
}

__device__ __forceinline__ void mfma_chunk(const u64* q, const f16* w0, const f16* w1,
                                           int c, f32x4& acc0, f32x4& acc1)
{
    #pragma unroll
    for (int i = 0; i < 4; i++) {
        const int ks = c * 4 + i;
        f16x8 af;
        #pragma unroll
        for (int e = 0; e < 4; e++) {
            u64 v = q[i * 4 + e];
            // u64 = [tag|h0] | [tag|h1]<<32 -> pack h0,h1 into one dword
            ((u32*)&af)[e] = (u32)(v & 0xffffu) | ((u32)(v >> 16) & 0xffff0000u);
        }
        f16x8 bf0 = *(const f16x8*)(w0 + ks * 32);   // LDS ds_read_b128
        f16x8 bf1 = *(const f16x8*)(w1 + ks * 32);
        acc0 = __builtin_amdgcn_mfma_f32_16x16x32_f16(af, bf0, acc0, 0, 0, 0);
        acc1 = __builtin_amdgcn_mfma_f32_16x16x32_f16(af, bf1, acc1, 0, 0, 0);
    }
}

extern "C" __global__ __launch_bounds__(256, 1)
void esn_kernel(const float* __restrict__ x, const float* __restrict__ Win,
                const float* __restrict__ Wres, float* __restrict__ out,
                u32* ht0, u32* ht1)
{
    extern __shared__ char lds[];
    f16*   Wr   = (f16*)(lds + LDS_WRES);    // [ROWS][WPAD]
    f16*   Whi  = (f16*)(lds + LDS_WINHI);   // [ROWS][IPAD]
    f16*   Wlo  = (f16*)(lds + LDS_WINLO);   // [ROWS][IPAD]
    float* part = (float*)(lds + LDS_PART);  // [4][BATS][PPAD]

    const int tid  = threadIdx.x;
    const int wg   = blockIdx.x;
    const int j    = wg & 63;       // row group
    const int bg   = wg >> 6;       // batch group
    const int r0   = j * ROWS;
    const int b0   = bg * BATS;
    const int wv   = tid >> 6;      // wave 0..3
    const int lane = tid & 63;
    const int lm   = lane & 15;     // A: m index / B: n index / C: col index
    const int quad = lane >> 4;     // 0..3

    // ---- one-time init: stage W_res slice (fp32 -> fp16) into LDS ----
    for (int idx = tid; idx < ROWS * (H_ / 4); idx += 256) {
        int r  = idx >> 9;          // 512 float4 per row
        int c4 = idx & 511;
        const float4 v = ((const float4*)(Wres + (size_t)(r0 + r) * H_))[c4];
        f16* dst = Wr + r * WPAD + c4 * 4;
        dst[0] = (f16)v.x; dst[1] = (f16)v.y; dst[2] = (f16)v.z; dst[3] = (f16)v.w;
    }
    // ---- W_in slice as fp16 hi + lo (precision split) ----
    for (int idx = tid; idx < ROWS * (I_ / 4); idx += 256) {
        int r  = idx >> 5;          // 32 float4 per row
        int c4 = idx & 31;
        const float4 v = ((const float4*)(Win + (size_t)(r0 + r) * I_))[c4];
        float vv[4] = {v.x, v.y, v.z, v.w};
        f16* dh = Whi + r * IPAD + c4 * 4;
        f16* dl = Wlo + r * IPAD + c4 * 4;
        #pragma unroll
        for (int q = 0; q < 4; q++) {
            f16 hi = (f16)vv[q];
            dh[q] = hi;
            dl[q] = (f16)(vv[q] - (float)hi);
        }
    }
    __syncthreads();

    for (int t = 0; t < T_; t++) {
        const u32* hrd = (t & 1) ? ht1 : ht0;   // expect tag == t
        u32*       hwr = (t & 1) ? ht0 : ht1;   // write tag t+1
        const u64  E   = ((u64)(u32)t << 16) | ((u64)(u32)t << 48);

        // lane's h base: batch (b0+lm), k-range [wv*512, +512) halves
        const u64* hb = (const u64*)hrd + ((size_t)(b0 + lm) << 10)
                      + (wv << 8) + (quad << 2);

        f32x4 acc0 = {0.f, 0.f, 0.f, 0.f};
        f32x4 acc1 = {0.f, 0.f, 0.f, 0.f};

        // ---- pipeline: issue chunks 0,1 speculatively; x-part hides latency ----
        u64 q0[16], q1[16];
        load_chunk(q0, hb);
        load_chunk(q1, hb + 64);

        // ---- x_t @ W_in^T with fp16 hi/lo split ----
        {
            const int kin = wv * 32 + quad * 8;
            const float* xp = x + ((size_t)(b0 + lm) * T_ + t) * I_ + kin;
            float xf[8];
            *(float4*)(xf)     = *(const float4*)(xp);
            *(float4*)(xf + 4) = *(const float4*)(xp + 4);
            f16x8 xhi, xlo;
            #pragma unroll
            for (int qq = 0; qq < 8; qq++) {
                f16 hi = (f16)xf[qq];
                xhi[qq] = hi;
                xlo[qq] = (f16)(xf[qq] - (float)hi);
            }
            f16x8 bh0 = *(const f16x8*)(Whi + lm * IPAD + kin);
            f16x8 bh1 = *(const f16x8*)(Whi + (lm + 16) * IPAD + kin);
            f16x8 bl0 = *(const f16x8*)(Wlo + lm * IPAD + kin);
            f16x8 bl1 = *(const f16x8*)(Wlo + (lm + 16) * IPAD + kin);
            acc0 = __builtin_amdgcn_mfma_f32_16x16x32_f16(xhi, bh0, acc0, 0, 0, 0);
            acc1 = __builtin_amdgcn_mfma_f32_16x16x32_f16(xhi, bh1, acc1, 0, 0, 0);
            acc0 = __builtin_amdgcn_mfma_f32_16x16x32_f16(xlo, bh0, acc0, 0, 0, 0);
            acc1 = __builtin_amdgcn_mfma_f32_16x16x32_f16(xlo, bh1, acc1, 0, 0, 0);
            acc0 = __builtin_amdgcn_mfma_f32_16x16x32_f16(xhi, bl0, acc0, 0, 0, 0);
            acc1 = __builtin_amdgcn_mfma_f32_16x16x32_f16(xhi, bl1, acc1, 0, 0, 0);
        }

        // ---- h_{t-1} @ W_res^T, 4 chunks, double-buffered validate+consume ----
        {
            const f16* w0 = Wr + lm * WPAD + wv * 512 + quad * 8;
            const f16* w1 = Wr + (lm + 16) * WPAD + wv * 512 + quad * 8;

            check_retry(q0, hb, E);
            mfma_chunk(q0, w0, w1, 0, acc0, acc1);
            load_chunk(q0, hb + 128);                 // chunk 2 into buf0

            check_retry(q1, hb + 64, E);
            mfma_chunk(q1, w0, w1, 1, acc0, acc1);
            load_chunk(q1, hb + 192);                 // chunk 3 into buf1

            check_retry(q0, hb + 128, E);
            mfma_chunk(q0, w0, w1, 2, acc0, acc1);

            check_retry(q1, hb + 192, E);
            mfma_chunk(q1, w0, w1, 3, acc0, acc1);
        }

        // ---- per-wave partials to LDS (C/D layout: col=lane&15, row=quad*4+reg) ----
        {
            float* pw = part + wv * (BATS * PPAD);
            #pragma unroll
            for (int r = 0; r < 4; r++) {
                int m = quad * 4 + r;
                pw[m * PPAD + lm]      = acc0[r];
                pw[m * PPAD + 16 + lm] = acc1[r];
            }
        }
        __syncthreads();

        // ---- reduce 4 waves + tanh + tagged store (m = tid>>4, n pair = tid&15) ----
        {
            const int m = tid >> 4;
            const int n = (tid & 15) * 2;
            const int o = m * PPAD + n;
            float s0 = part[o]     + part[BATS * PPAD + o]     + part[2 * BATS * PPAD + o]
                     + part[3 * BATS * PPAD + o];
            float s1 = part[o + 1] + part[BATS * PPAD + o + 1] + part[2 * BATS * PPAD + o + 1]
                     + part[3 * BATS * PPAD + o + 1];
            s0 = tanhf(s0);
            s1 = tanhf(s1);
            if (t == T_ - 1) {
                // final step: plain fp32 to out. Safe vs ht0 aliasing: reaching
                // t=511 required tag-511 from all same-bg peers => their t=510
                // ht0 reads are complete; other bgs touch disjoint batches.
                float* op = out + (size_t)(b0 + m) * H_ + r0 + n;
                op[0] = s0;
                op[1] = s1;
            } else {
                union { f16 f; unsigned short u; } c0, c1;
                c0.f = (f16)s0;
                c1.f = (f16)s1;
                const u32 tg = (u32)(t + 1) << 16;
                u64 pk = (u64)(tg | c0.u) | ((u64)(tg | c1.u) << 32);
                // fire-and-forget write-through; validity is in-band
                __hip_atomic_store((u64*)(hwr + (size_t)(b0 + m) * H_ + r0 + n),
                                   pk, __ATOMIC_RELAXED, __HIP_MEMORY_SCOPE_AGENT);
            }
        }

        // protect LDS partials from next step's writes (intra-WG only)
        __syncthreads();
    }
}

extern "C" void kernel_launch(void* const* d_in, const int* in_sizes, int n_in,
                              void* d_out, int out_size, void* d_ws, size_t ws_size,
                              hipStream_t stream)
{
    (void)in_sizes; (void)n_in; (void)out_size; (void)ws_size;
    const float* x    = (const float*)d_in[0];
    const float* Win  = (const float*)d_in[1];
    const float* Wres = (const float*)d_in[2];
    float* out = (float*)d_out;

    // ht0 aliases d_out (B*H dwords = out_size floats); ht1 lives in d_ws.
    u32* ht0 = (u32*)d_out;
    u32* ht1 = (u32*)d_ws;

    // tag-0/value-0 init for step 0 (harness poisons both buffers pre-launch)
    hipMemsetAsync(d_out, 0, (size_t)B_ * H_ * sizeof(u32), stream);
    hipMemsetAsync(d_ws,  0, (size_t)B_ * H_ * sizeof(u32), stream);

    hipFuncSetAttribute((const void*)esn_kernel,
                        hipFuncAttributeMaxDynamicSharedMemorySize, LDS_TOTAL);

    void* args[] = {(void*)&x, (void*)&Win, (void*)&Wres, (void*)&out,
                    (void*)&ht0, (void*)&ht1};
    hipLaunchCooperativeKernel((const void*)esn_kernel, dim3(NWG), dim3(256),
                               args, LDS_TOTAL, stream);
}

// Round 10
// 3404.268 us; speedup vs baseline: 1.5001x; 1.5001x over previous
//
#include <hip/hip_runtime.h>

// ESN recurrence on MI355X: h_t = tanh(x_t @ W_in^T + h_{t-1} @ W_res^T)
// B=64, T=512, I=128, H=2048. Persistent cooperative kernel, 256 WGs (1/CU).
// WG (bg,j): batches [bg*16, bg*16+16), rows [j*32, j*32+32).
// R10 = R9 with the consumer h base-address fix (R9 halved the u64 offsets:
// row = 512 u64 (<<9), wave = 128 u64 (<<7), quad = 2 u64 (<<1)).
// Scheme: 1-bit in-band tag in the fp16 mantissa LSB. Depth-2 ping-pong =>
// stale data is exactly h_{t-2}, and (t>>1)&1 != ((t-2)>>1)&1 => one bit
// proves freshness. Producers: fire-and-forget u64 agent stores (4 tagged
// halves). Consumers: speculative agent loads + masked retry; LSB-clear; the
// u64 pair IS the MFMA A-fragment. No fences, no flags, no publish barrier.
// Init: buffer0 = 0x00 (h_0 = 0, bit 0 fresh for t=0); buffer1 = 0x01 bytes
// (bit 1 => t=1 consumers block until real h_1 arrives carrying bit 0).

#define B_ 64
#define T_ 512
#define I_ 128
#define H_ 2048
#define NWG 256
#define ROWS 32          // output rows per WG
#define BATS 16          // batches per WG
#define WPAD 2056        // 2048 + 8 halves row pad
#define IPAD 136         // 128 + 8 halves row pad
#define PPAD 33          // partial row pad (break 32-bank stride)

typedef _Float16 f16;
typedef f16 f16x8 __attribute__((ext_vector_type(8)));
typedef float f32x4 __attribute__((ext_vector_type(4)));
typedef unsigned long long u64;
typedef unsigned int u32;
typedef unsigned short u16;

#define TAGM 0x0001000100010001ULL   // mantissa-LSB mask, 4 halves per u64

// LDS layout (bytes):
//   Wres  : ROWS*WPAD*2           = 131584
//   Win_hi: ROWS*IPAD*2           =   8704
//   Win_lo: ROWS*IPAD*2           =   8704
//   part  : 4*BATS*PPAD*4         =   8448
#define LDS_WRES   0
#define LDS_WINHI  131584
#define LDS_WINLO  (131584 + 8704)
#define LDS_PART   (131584 + 17408)
#define LDS_TOTAL  (131584 + 17408 + 8448)

__device__ __forceinline__ void load_chunk8(u64* q, const u64* cp)
{
    // chunk = 4 ks-iterations x 2 u64 (8 halves = one MFMA A-fragment)
    #pragma unroll
    for (int i = 0; i < 4; i++)
        #pragma unroll
        for (int e = 0; e < 2; e++)
            q[i * 2 + e] = __hip_atomic_load(cp + i * 8 + e, __ATOMIC_RELAXED,
                                             __HIP_MEMORY_SCOPE_AGENT);
}

__device__ __forceinline__ void check_retry8(u64* q, const u64* cp, u64 E)
{
    for (;;) {
        u64 bad = 0;
        #pragma unroll
        for (int i = 0; i < 8; i++) bad |= (q[i] & TAGM) ^ E;
        if (__all(bad == 0)) break;
        if (bad) {                      // only stale lanes re-load (exec-masked)
            __builtin_amdgcn_s_sleep(1);
            load_chunk8(q, cp);
        }
    }
}

__device__ __forceinline__ void mfma_chunk4(const u64* q, const f16* w0, const f16* w1,
                                            int c, f32x4& acc0, f32x4& acc1)
{
    #pragma unroll
    for (int i = 0; i < 4; i++) {
        const int ks = c * 4 + i;
        f16x8 af;
        ((u64*)&af)[0] = q[i * 2]     & ~TAGM;   // clear tag bits (<=1 ulp)
        ((u64*)&af)[1] = q[i * 2 + 1] & ~TAGM;
        f16x8 bf0 = *(const f16x8*)(w0 + ks * 32);   // LDS ds_read_b128
        f16x8 bf1 = *(const f16x8*)(w1 + ks * 32);
        acc0 = __builtin_amdgcn_mfma_f32_16x16x32_f16(af, bf0, acc0, 0, 0, 0);
        acc1 = __builtin_amdgcn_mfma_f32_16x16x32_f16(af, bf1, acc1, 0, 0, 0);
    }
}

extern "C" __global__ __launch_bounds__(256, 1)
void esn_kernel(const float* __restrict__ x, const float* __restrict__ Win,
                const float* __restrict__ Wres, float* __restrict__ out,
                u16* ht0, u16* ht1)
{
    extern __shared__ char lds[];
    f16*   Wr   = (f16*)(lds + LDS_WRES);    // [ROWS][WPAD]
    f16*   Whi  = (f16*)(lds + LDS_WINHI);   // [ROWS][IPAD]
    f16*   Wlo  = (f16*)(lds + LDS_WINLO);   // [ROWS][IPAD]
    float* part = (float*)(lds + LDS_PART);  // [4][BATS][PPAD]

    const int tid  = threadIdx.x;
    const int wg   = blockIdx.x;
    const int j    = wg & 63;       // row group
    const int bg   = wg >> 6;       // batch group
    const int r0   = j * ROWS;
    const int b0   = bg * BATS;
    const int wv   = tid >> 6;      // wave 0..3
    const int lane = tid & 63;
    const int lm   = lane & 15;     // A: m index / B: n index / C: col index
    const int quad = lane >> 4;     // 0..3

    // ---- one-time init: stage W_res slice (fp32 -> fp16) into LDS ----
    for (int idx = tid; idx < ROWS * (H_ / 4); idx += 256) {
        int r  = idx >> 9;          // 512 float4 per row
        int c4 = idx & 511;
        const float4 v = ((const float4*)(Wres + (size_t)(r0 + r) * H_))[c4];
        f16* dst = Wr + r * WPAD + c4 * 4;
        dst[0] = (f16)v.x; dst[1] = (f16)v.y; dst[2] = (f16)v.z; dst[3] = (f16)v.w;
    }
    // ---- W_in slice as fp16 hi + lo (precision split) ----
    for (int idx = tid; idx < ROWS * (I_ / 4); idx += 256) {
        int r  = idx >> 5;          // 32 float4 per row
        int c4 = idx & 31;
        const float4 v = ((const float4*)(Win + (size_t)(r0 + r) * I_))[c4];
        float vv[4] = {v.x, v.y, v.z, v.w};
        f16* dh = Whi + r * IPAD + c4 * 4;
        f16* dl = Wlo + r * IPAD + c4 * 4;
        #pragma unroll
        for (int q = 0; q < 4; q++) {
            f16 hi = (f16)vv[q];
            dh[q] = hi;
            dl[q] = (f16)(vv[q] - (float)hi);
        }
    }
    __syncthreads();

    for (int t = 0; t < T_; t++) {
        const u16* hrd = (t & 1) ? ht1 : ht0;   // fresh data carries bit (t>>1)&1
        u16*       hwr = (t & 1) ? ht0 : ht1;   // write h_{t+1}, bit ((t+1)>>1)&1
        const u64  E   = ((t >> 1) & 1) ? TAGM : 0ULL;

        // lane's h base in u64 units: batch row = 512 u64 (<<9), wave k-range
        // = 128 u64 (<<7), quad = 2 u64 (<<1).  [R9's bug: <<8 / <<6 / +quad]
        const u64* hb = (const u64*)hrd + ((size_t)(b0 + lm) << 9)
                      + (wv << 7) + (quad << 1);

        f32x4 acc0 = {0.f, 0.f, 0.f, 0.f};
        f32x4 acc1 = {0.f, 0.f, 0.f, 0.f};

        // ---- pipeline: issue chunks 0,1 speculatively; x-part hides latency ----
        u64 q0[8], q1[8];
        load_chunk8(q0, hb);
        load_chunk8(q1, hb + 32);

        // ---- x_t @ W_in^T with fp16 hi/lo split ----
        {
            const int kin = wv * 32 + quad * 8;
            const float* xp = x + ((size_t)(b0 + lm) * T_ + t) * I_ + kin;
            float xf[8];
            *(float4*)(xf)     = *(const float4*)(xp);
            *(float4*)(xf + 4) = *(const float4*)(xp + 4);
            f16x8 xhi, xlo;
            #pragma unroll
            for (int qq = 0; qq < 8; qq++) {
                f16 hi = (f16)xf[qq];
                xhi[qq] = hi;
                xlo[qq] = (f16)(xf[qq] - (float)hi);
            }
            f16x8 bh0 = *(const f16x8*)(Whi + lm * IPAD + kin);
            f16x8 bh1 = *(const f16x8*)(Whi + (lm + 16) * IPAD + kin);
            f16x8 bl0 = *(const f16x8*)(Wlo + lm * IPAD + kin);
            f16x8 bl1 = *(const f16x8*)(Wlo + (lm + 16) * IPAD + kin);
            acc0 = __builtin_amdgcn_mfma_f32_16x16x32_f16(xhi, bh0, acc0, 0, 0, 0);
            acc1 = __builtin_amdgcn_mfma_f32_16x16x32_f16(xhi, bh1, acc1, 0, 0, 0);
            acc0 = __builtin_amdgcn_mfma_f32_16x16x32_f16(xlo, bh0, acc0, 0, 0, 0);
            acc1 = __builtin_amdgcn_mfma_f32_16x16x32_f16(xlo, bh1, acc1, 0, 0, 0);
            acc0 = __builtin_amdgcn_mfma_f32_16x16x32_f16(xhi, bl0, acc0, 0, 0, 0);
            acc1 = __builtin_amdgcn_mfma_f32_16x16x32_f16(xhi, bl1, acc1, 0, 0, 0);
        }

        // ---- h_{t-1} @ W_res^T, 4 chunks, double-buffered validate+consume ----
        {
            const f16* w0 = Wr + lm * WPAD + wv * 512 + quad * 8;
            const f16* w1 = Wr + (lm + 16) * WPAD + wv * 512 + quad * 8;

            check_retry8(q0, hb, E);
            mfma_chunk4(q0, w0, w1, 0, acc0, acc1);
            load_chunk8(q0, hb + 64);                 // chunk 2 into buf0

            check_retry8(q1, hb + 32, E);
            mfma_chunk4(q1, w0, w1, 1, acc0, acc1);
            load_chunk8(q1, hb + 96);                 // chunk 3 into buf1

            check_retry8(q0, hb + 64, E);
            mfma_chunk4(q0, w0, w1, 2, acc0, acc1);

            check_retry8(q1, hb + 96, E);
            mfma_chunk4(q1, w0, w1, 3, acc0, acc1);
        }

        // ---- per-wave partials to LDS (C/D layout: col=lane&15, row=quad*4+reg) ----
        {
            float* pw = part + wv * (BATS * PPAD);
            #pragma unroll
            for (int r = 0; r < 4; r++) {
                int m = quad * 4 + r;
                pw[m * PPAD + lm]      = acc0[r];
                pw[m * PPAD + 16 + lm] = acc1[r];
            }
        }
        __syncthreads();

        // ---- reduce 4 waves + tanh + store ----
        if (t == T_ - 1) {
            // final step: fp32 to out, 2 per thread (m = tid>>4, n = (tid&15)*2)
            const int m = tid >> 4;
            const int n = (tid & 15) * 2;
            const int o = m * PPAD + n;
            float s0 = part[o]     + part[BATS * PPAD + o]     + part[2 * BATS * PPAD + o]
                     + part[3 * BATS * PPAD + o];
            float s1 = part[o + 1] + part[BATS * PPAD + o + 1] + part[2 * BATS * PPAD + o + 1]
                     + part[3 * BATS * PPAD + o + 1];
            float* op = out + (size_t)(b0 + m) * H_ + r0 + n;
            op[0] = tanhf(s0);
            op[1] = tanhf(s1);
        } else if (tid < 128) {
            // h store: one u64 = 4 tagged halves per thread (m = tid>>3, n0 = (tid&7)*4)
            const int m  = tid >> 3;
            const int n0 = (tid & 7) * 4;
            const u16 bit = (u16)(((t + 1) >> 1) & 1);
            union { u16 h[4]; u64 u; } pk;
            #pragma unroll
            for (int e = 0; e < 4; e++) {
                const int o = m * PPAD + n0 + e;
                float s = part[o] + part[BATS * PPAD + o] + part[2 * BATS * PPAD + o]
                        + part[3 * BATS * PPAD + o];
                union { f16 f; u16 u; } cv;
                cv.f = (f16)tanhf(s);
                pk.h[e] = (u16)((cv.u & 0xFFFEu) | bit);   // mantissa LSB = tag
            }
            // fire-and-forget write-through; validity is in-band
            __hip_atomic_store((u64*)(hwr + (size_t)(b0 + m) * H_ + r0 + n0),
                               pk.u, __ATOMIC_RELAXED, __HIP_MEMORY_SCOPE_AGENT);
        }

        // protect LDS partials from next step's writes (intra-WG only)
        __syncthreads();
    }
}

extern "C" void kernel_launch(void* const* d_in, const int* in_sizes, int n_in,
                              void* d_out, int out_size, void* d_ws, size_t ws_size,
                              hipStream_t stream)
{
    (void)in_sizes; (void)n_in; (void)out_size; (void)ws_size;
    const float* x    = (const float*)d_in[0];
    const float* Win  = (const float*)d_in[1];
    const float* Wres = (const float*)d_in[2];
    float* out = (float*)d_out;

    u16* ht0 = (u16*)d_ws;                        // [64][2048] fp16, LSB = tag
    u16* ht1 = ht0 + (size_t)B_ * H_;

    // buffer0: 0x00 bytes -> h_0 = 0, tag bit 0 (fresh for t=0).
    // buffer1: 0x01 bytes -> tag bit 1 => t=1 consumers block until real h_1.
    hipMemsetAsync(d_ws, 0x00, (size_t)B_ * H_ * sizeof(u16), stream);
    hipMemsetAsync((char*)d_ws + (size_t)B_ * H_ * sizeof(u16), 0x01,
                   (size_t)B_ * H_ * sizeof(u16), stream);

    hipFuncSetAttribute((const void*)esn_kernel,
                        hipFuncAttributeMaxDynamicSharedMemorySize, LDS_TOTAL);

    void* args[] = {(void*)&x, (void*)&Win, (void*)&Wres, (void*)&out,
                    (void*)&ht0, (void*)&ht1};
    hipLaunchCooperativeKernel((const void*)esn_kernel, dim3(NWG), dim3(256),
                               args, LDS_TOTAL, stream);
}

// Round 11
// 3314.066 us; speedup vs baseline: 1.5409x; 1.0272x over previous
//
#include <hip/hip_runtime.h>

// ESN recurrence on MI355X: h_t = tanh(x_t @ W_in^T + h_{t-1} @ W_res^T)
// B=64, T=512, I=128, H=2048. Persistent cooperative kernel, 256 WGs (1/CU).
// WG (bg,j): batches [bg*16, bg*16+16), rows [j*32, j*32+32).
// R11 = R10 protocol (1-bit in-band tag in fp16 mantissa LSB, depth-2
// ping-pong, fire-and-forget producer stores) with the consumer loads
// switched from per-lane 8B ATOMICS (uncoalesced: 2048 lane-transactions
// per wave per step -> transaction-rate bound, the 0.107us/load term in
// R6/R8/R10 timings) to COALESCED global_load_dwordx4 sc0 sc1 (16 line
// requests per wave per instr, L1/L2-bypassing, reads the coherence point).
// Safe at any width: EVERY u16 carries its own tag bit, so torn/stale data
// at any granularity is detected and retried. The 16B load is exactly one
// MFMA A-fragment after LSB-clear.

#define B_ 64
#define T_ 512
#define I_ 128
#define H_ 2048
#define NWG 256
#define ROWS 32          // output rows per WG
#define BATS 16          // batches per WG
#define WPAD 2056        // 2048 + 8 halves row pad
#define IPAD 136         // 128 + 8 halves row pad
#define PPAD 33          // partial row pad (break 32-bank stride)

typedef _Float16 f16;
typedef f16 f16x8 __attribute__((ext_vector_type(8)));
typedef float f32x4 __attribute__((ext_vector_type(4)));
typedef unsigned long long u64;
typedef unsigned int u32;
typedef unsigned short u16;
typedef u32 u32x4 __attribute__((ext_vector_type(4)));

#define TAG32 0x00010001u            // mantissa-LSB mask, 2 halves per dword

// LDS layout (bytes):
//   Wres  : ROWS*WPAD*2           = 131584
//   Win_hi: ROWS*IPAD*2           =   8704
//   Win_lo: ROWS*IPAD*2           =   8704
//   part  : 4*BATS*PPAD*4         =   8448
#define LDS_WRES   0
#define LDS_WINHI  131584
#define LDS_WINLO  (131584 + 8704)
#define LDS_PART   (131584 + 17408)
#define LDS_TOTAL  (131584 + 17408 + 8448)

extern "C" __global__ __launch_bounds__(256, 1)
void esn_kernel(const float* __restrict__ x, const float* __restrict__ Win,
                const float* __restrict__ Wres, float* __restrict__ out,
                u16* ht0, u16* ht1)
{
    extern __shared__ char lds[];
    f16*   Wr   = (f16*)(lds + LDS_WRES);    // [ROWS][WPAD]
    f16*   Whi  = (f16*)(lds + LDS_WINHI);   // [ROWS][IPAD]
    f16*   Wlo  = (f16*)(lds + LDS_WINLO);   // [ROWS][IPAD]
    float* part = (float*)(lds + LDS_PART);  // [4][BATS][PPAD]

    const int tid  = threadIdx.x;
    const int wg   = blockIdx.x;
    const int j    = wg & 63;       // row group
    const int bg   = wg >> 6;       // batch group
    const int r0   = j * ROWS;
    const int b0   = bg * BATS;
    const int wv   = tid >> 6;      // wave 0..3
    const int lane = tid & 63;
    const int lm   = lane & 15;     // A: m index / B: n index / C: col index
    const int quad = lane >> 4;     // 0..3

    // ---- one-time init: stage W_res slice (fp32 -> fp16) into LDS ----
    for (int idx = tid; idx < ROWS * (H_ / 4); idx += 256) {
        int r  = idx >> 9;          // 512 float4 per row
        int c4 = idx & 511;
        const float4 v = ((const float4*)(Wres + (size_t)(r0 + r) * H_))[c4];
        f16* dst = Wr + r * WPAD + c4 * 4;
        dst[0] = (f16)v.x; dst[1] = (f16)v.y; dst[2] = (f16)v.z; dst[3] = (f16)v.w;
    }
    // ---- W_in slice as fp16 hi + lo (precision split) ----
    for (int idx = tid; idx < ROWS * (I_ / 4); idx += 256) {
        int r  = idx >> 5;          // 32 float4 per row
        int c4 = idx & 31;
        const float4 v = ((const float4*)(Win + (size_t)(r0 + r) * I_))[c4];
        float vv[4] = {v.x, v.y, v.z, v.w};
        f16* dh = Whi + r * IPAD + c4 * 4;
        f16* dl = Wlo + r * IPAD + c4 * 4;
        #pragma unroll
        for (int q = 0; q < 4; q++) {
            f16 hi = (f16)vv[q];
            dh[q] = hi;
            dl[q] = (f16)(vv[q] - (float)hi);
        }
    }
    __syncthreads();

    for (int t = 0; t < T_; t++) {
        const u16* hrd = (t & 1) ? ht1 : ht0;   // fresh data carries bit (t>>1)&1
        u16*       hwr = (t & 1) ? ht0 : ht1;   // write h_{t+1}, bit ((t+1)>>1)&1
        const u32  E32 = ((t >> 1) & 1) ? TAG32 : 0u;

        // lane's h base in BYTES: batch row = 4096 B, wave k-range = 1024 B,
        // quad = 16 B. Fragment ks: +ks*64 B, 16 B = one MFMA A-fragment.
        // Coalescing: per instr (fixed ks), 4 quads x 16B = one full 64B line
        // per lm group -> 16 line requests per wave.
        const u64 hb = (u64)hrd + ((u64)(b0 + lm) << 12) + (wv << 10) + (quad << 4);

        f32x4 acc0 = {0.f, 0.f, 0.f, 0.f};
        f32x4 acc1 = {0.f, 0.f, 0.f, 0.f};

        // ---- issue all 16 coherent coalesced fragment loads (speculative) ----
        u32x4 v[16];
        #pragma unroll
        for (int ks = 0; ks < 16; ks++) {
            asm volatile("global_load_dwordx4 %0, %1, off sc0 sc1"
                         : "=&v"(v[ks]) : "v"(hb + (u64)(ks * 64)));
        }

        // ---- x_t @ W_in^T with fp16 hi/lo split (hides h-load latency) ----
        {
            const int kin = wv * 32 + quad * 8;
            const float* xp = x + ((size_t)(b0 + lm) * T_ + t) * I_ + kin;
            float xf[8];
            *(float4*)(xf)     = *(const float4*)(xp);
            *(float4*)(xf + 4) = *(const float4*)(xp + 4);
            f16x8 xhi, xlo;
            #pragma unroll
            for (int qq = 0; qq < 8; qq++) {
                f16 hi = (f16)xf[qq];
                xhi[qq] = hi;
                xlo[qq] = (f16)(xf[qq] - (float)hi);
            }
            f16x8 bh0 = *(const f16x8*)(Whi + lm * IPAD + kin);
            f16x8 bh1 = *(const f16x8*)(Whi + (lm + 16) * IPAD + kin);
            f16x8 bl0 = *(const f16x8*)(Wlo + lm * IPAD + kin);
            f16x8 bl1 = *(const f16x8*)(Wlo + (lm + 16) * IPAD + kin);
            acc0 = __builtin_amdgcn_mfma_f32_16x16x32_f16(xhi, bh0, acc0, 0, 0, 0);
            acc1 = __builtin_amdgcn_mfma_f32_16x16x32_f16(xhi, bh1, acc1, 0, 0, 0);
            acc0 = __builtin_amdgcn_mfma_f32_16x16x32_f16(xlo, bh0, acc0, 0, 0, 0);
            acc1 = __builtin_amdgcn_mfma_f32_16x16x32_f16(xlo, bh1, acc1, 0, 0, 0);
            acc0 = __builtin_amdgcn_mfma_f32_16x16x32_f16(xhi, bl0, acc0, 0, 0, 0);
            acc1 = __builtin_amdgcn_mfma_f32_16x16x32_f16(xhi, bl1, acc1, 0, 0, 0);
        }

        // ---- wait, validate every 16-bit tag, per-lane masked retry ----
        asm volatile("s_waitcnt vmcnt(0)" ::: "memory");
        for (;;) {
            u32 bad = 0;
            #pragma unroll
            for (int ks = 0; ks < 16; ks++)
                #pragma unroll
                for (int e = 0; e < 4; e++)
                    bad |= (v[ks][e] & TAG32) ^ E32;
            if (__all(bad == 0)) break;
            if (bad) {                       // only stale lanes re-load
                __builtin_amdgcn_s_sleep(1);
                #pragma unroll
                for (int ks = 0; ks < 16; ks++) {
                    asm volatile("global_load_dwordx4 %0, %1, off sc0 sc1"
                                 : "=&v"(v[ks]) : "v"(hb + (u64)(ks * 64)));
                }
            }
            asm volatile("s_waitcnt vmcnt(0)" ::: "memory");
        }

        // ---- h_{t-1} @ W_res^T: LSB-clear -> A-fragment, 32 MFMAs ----
        {
            const f16* w0 = Wr + lm * WPAD + wv * 512 + quad * 8;
            const f16* w1 = Wr + (lm + 16) * WPAD + wv * 512 + quad * 8;
            #pragma unroll
            for (int ks = 0; ks < 16; ks++) {
                f16x8 af;
                #pragma unroll
                for (int e = 0; e < 4; e++)
                    ((u32*)&af)[e] = v[ks][e] & ~TAG32;   // clear tag (<=1 ulp)
                f16x8 bf0 = *(const f16x8*)(w0 + ks * 32);   // LDS ds_read_b128
                f16x8 bf1 = *(const f16x8*)(w1 + ks * 32);
                acc0 = __builtin_amdgcn_mfma_f32_16x16x32_f16(af, bf0, acc0, 0, 0, 0);
                acc1 = __builtin_amdgcn_mfma_f32_16x16x32_f16(af, bf1, acc1, 0, 0, 0);
            }
        }

        // ---- per-wave partials to LDS (C/D layout: col=lane&15, row=quad*4+reg) ----
        {
            float* pw = part + wv * (BATS * PPAD);
            #pragma unroll
            for (int r = 0; r < 4; r++) {
                int m = quad * 4 + r;
                pw[m * PPAD + lm]      = acc0[r];
                pw[m * PPAD + 16 + lm] = acc1[r];
            }
        }
        __syncthreads();

        // ---- reduce 4 waves + tanh + store ----
        if (t == T_ - 1) {
            // final step: fp32 to out, 2 per thread (m = tid>>4, n = (tid&15)*2)
            const int m = tid >> 4;
            const int n = (tid & 15) * 2;
            const int o = m * PPAD + n;
            float s0 = part[o]     + part[BATS * PPAD + o]     + part[2 * BATS * PPAD + o]
                     + part[3 * BATS * PPAD + o];
            float s1 = part[o + 1] + part[BATS * PPAD + o + 1] + part[2 * BATS * PPAD + o + 1]
                     + part[3 * BATS * PPAD + o + 1];
            float* op = out + (size_t)(b0 + m) * H_ + r0 + n;
            op[0] = tanhf(s0);
            op[1] = tanhf(s1);
        } else if (tid < 128) {
            // h store: one u64 = 4 tagged halves per thread (m = tid>>3, n0 = (tid&7)*4)
            const int m  = tid >> 3;
            const int n0 = (tid & 7) * 4;
            const u16 bit = (u16)(((t + 1) >> 1) & 1);
            union { u16 h[4]; u64 u; } pk;
            #pragma unroll
            for (int e = 0; e < 4; e++) {
                const int o = m * PPAD + n0 + e;
                float s = part[o] + part[BATS * PPAD + o] + part[2 * BATS * PPAD + o]
                        + part[3 * BATS * PPAD + o];
                union { f16 f; u16 u; } cv;
                cv.f = (f16)tanhf(s);
                pk.h[e] = (u16)((cv.u & 0xFFFEu) | bit);   // mantissa LSB = tag
            }
            // fire-and-forget write-through; validity is in-band
            __hip_atomic_store((u64*)(hwr + (size_t)(b0 + m) * H_ + r0 + n0),
                               pk.u, __ATOMIC_RELAXED, __HIP_MEMORY_SCOPE_AGENT);
        }

        // protect LDS partials from next step's writes (intra-WG only)
        __syncthreads();
    }
}

extern "C" void kernel_launch(void* const* d_in, const int* in_sizes, int n_in,
                              void* d_out, int out_size, void* d_ws, size_t ws_size,
                              hipStream_t stream)
{
    (void)in_sizes; (void)n_in; (void)out_size; (void)ws_size;
    const float* x    = (const float*)d_in[0];
    const float* Win  = (const float*)d_in[1];
    const float* Wres = (const float*)d_in[2];
    float* out = (float*)d_out;

    u16* ht0 = (u16*)d_ws;                        // [64][2048] fp16, LSB = tag
    u16* ht1 = ht0 + (size_t)B_ * H_;

    // buffer0: 0x00 bytes -> h_0 = 0, tag bit 0 (fresh for t=0).
    // buffer1: 0x01 bytes -> tag bit 1 => t=1 consumers block until real h_1.
    hipMemsetAsync(d_ws, 0x00, (size_t)B_ * H_ * sizeof(u16), stream);
    hipMemsetAsync((char*)d_ws + (size_t)B_ * H_ * sizeof(u16), 0x01,
                   (size_t)B_ * H_ * sizeof(u16), stream);

    hipFuncSetAttribute((const void*)esn_kernel,
                        hipFuncAttributeMaxDynamicSharedMemorySize, LDS_TOTAL);

    void* args[] = {(void*)&x, (void*)&Win, (void*)&Wres, (void*)&out,
                    (void*)&ht0, (void*)&ht1};
    hipLaunchCooperativeKernel((const void*)esn_kernel, dim3(NWG), dim3(256),
                               args, LDS_TOTAL, stream);
}

// Round 12
// 2604.774 us; speedup vs baseline: 1.9605x; 1.2723x over previous
//
#include <hip/hip_runtime.h>

// ESN recurrence on MI355X: h_t = tanh(x_t @ W_in^T + h_{t-1} @ W_res^T)
// B=64, T=512, I=128, H=2048. Persistent cooperative kernel, 256 WGs (1/CU).
// WG (bg,j): batches [bg*16, bg*16+16), rows [j*32, j*32+32).
// R12 = R11 (in-band 1-bit tag in fp16 mantissa LSB = the correctness
// guarantee) + FLAG HINT for cheap detection:
//  - producer: tagged h stores (fire-and-forget) -> __syncthreads (issue
//    order) -> tid0 fire-and-forget flag[parity][wg] = t+1. NO drain.
//  - consumer: spin on its 16 producers' flags (one per-lane dword/round,
//    ~10 VALU, bounded) -> issue 16 coalesced sc0sc1 h loads ONCE ->
//    validate tags -> rare retry absorbs flag-vs-h fabric skew.
// This separates detection cost (was: blind 1KB reissue + 192-VALU check
// per round) from store->visible latency v. If time stays ~6.5us/step, v
// is the floor and the next lever is XCD-local exchange.

#define B_ 64
#define T_ 512
#define I_ 128
#define H_ 2048
#define NWG 256
#define ROWS 32          // output rows per WG
#define BATS 16          // batches per WG
#define WPAD 2056        // 2048 + 8 halves row pad
#define IPAD 136         // 128 + 8 halves row pad
#define PPAD 33          // partial row pad (break 32-bank stride)
#define FSTRIDE 16       // flag stride in dwords (64 B line per producer)

typedef _Float16 f16;
typedef f16 f16x8 __attribute__((ext_vector_type(8)));
typedef float f32x4 __attribute__((ext_vector_type(4)));
typedef unsigned long long u64;
typedef unsigned int u32;
typedef unsigned short u16;
typedef u32 u32x4 __attribute__((ext_vector_type(4)));

#define TAG32 0x00010001u            // mantissa-LSB mask, 2 halves per dword

// LDS layout (bytes):
//   Wres  : ROWS*WPAD*2           = 131584
//   Win_hi: ROWS*IPAD*2           =   8704
//   Win_lo: ROWS*IPAD*2           =   8704
//   part  : 4*BATS*PPAD*4         =   8448
#define LDS_WRES   0
#define LDS_WINHI  131584
#define LDS_WINLO  (131584 + 8704)
#define LDS_PART   (131584 + 17408)
#define LDS_TOTAL  (131584 + 17408 + 8448)

extern "C" __global__ __launch_bounds__(256, 1)
void esn_kernel(const float* __restrict__ x, const float* __restrict__ Win,
                const float* __restrict__ Wres, float* __restrict__ out,
                u16* ht0, u16* ht1, int* flags)
{
    extern __shared__ char lds[];
    f16*   Wr   = (f16*)(lds + LDS_WRES);    // [ROWS][WPAD]
    f16*   Whi  = (f16*)(lds + LDS_WINHI);   // [ROWS][IPAD]
    f16*   Wlo  = (f16*)(lds + LDS_WINLO);   // [ROWS][IPAD]
    float* part = (float*)(lds + LDS_PART);  // [4][BATS][PPAD]

    const int tid  = threadIdx.x;
    const int wg   = blockIdx.x;
    const int j    = wg & 63;       // row group
    const int bg   = wg >> 6;       // batch group
    const int r0   = j * ROWS;
    const int b0   = bg * BATS;
    const int wv   = tid >> 6;      // wave 0..3
    const int lane = tid & 63;
    const int lm   = lane & 15;     // A: m index / B: n index / C: col index
    const int quad = lane >> 4;     // 0..3

    // ---- one-time init: stage W_res slice (fp32 -> fp16) into LDS ----
    for (int idx = tid; idx < ROWS * (H_ / 4); idx += 256) {
        int r  = idx >> 9;          // 512 float4 per row
        int c4 = idx & 511;
        const float4 v = ((const float4*)(Wres + (size_t)(r0 + r) * H_))[c4];
        f16* dst = Wr + r * WPAD + c4 * 4;
        dst[0] = (f16)v.x; dst[1] = (f16)v.y; dst[2] = (f16)v.z; dst[3] = (f16)v.w;
    }
    // ---- W_in slice as fp16 hi + lo (precision split) ----
    for (int idx = tid; idx < ROWS * (I_ / 4); idx += 256) {
        int r  = idx >> 5;          // 32 float4 per row
        int c4 = idx & 31;
        const float4 v = ((const float4*)(Win + (size_t)(r0 + r) * I_))[c4];
        float vv[4] = {v.x, v.y, v.z, v.w};
        f16* dh = Whi + r * IPAD + c4 * 4;
        f16* dl = Wlo + r * IPAD + c4 * 4;
        #pragma unroll
        for (int q = 0; q < 4; q++) {
            f16 hi = (f16)vv[q];
            dh[q] = hi;
            dl[q] = (f16)(vv[q] - (float)hi);
        }
    }
    __syncthreads();

    for (int t = 0; t < T_; t++) {
        const u16* hrd = (t & 1) ? ht1 : ht0;   // fresh data carries bit (t>>1)&1
        u16*       hwr = (t & 1) ? ht0 : ht1;   // write h_{t+1}, bit ((t+1)>>1)&1
        const u32  E32 = ((t >> 1) & 1) ? TAG32 : 0u;

        f32x4 acc0 = {0.f, 0.f, 0.f, 0.f};
        f32x4 acc1 = {0.f, 0.f, 0.f, 0.f};

        // ---- x_t @ W_in^T with fp16 hi/lo split (before the wait) ----
        {
            const int kin = wv * 32 + quad * 8;
            const float* xp = x + ((size_t)(b0 + lm) * T_ + t) * I_ + kin;
            float xf[8];
            *(float4*)(xf)     = *(const float4*)(xp);
            *(float4*)(xf + 4) = *(const float4*)(xp + 4);
            f16x8 xhi, xlo;
            #pragma unroll
            for (int qq = 0; qq < 8; qq++) {
                f16 hi = (f16)xf[qq];
                xhi[qq] = hi;
                xlo[qq] = (f16)(xf[qq] - (float)hi);
            }
            f16x8 bh0 = *(const f16x8*)(Whi + lm * IPAD + kin);
            f16x8 bh1 = *(const f16x8*)(Whi + (lm + 16) * IPAD + kin);
            f16x8 bl0 = *(const f16x8*)(Wlo + lm * IPAD + kin);
            f16x8 bl1 = *(const f16x8*)(Wlo + (lm + 16) * IPAD + kin);
            acc0 = __builtin_amdgcn_mfma_f32_16x16x32_f16(xhi, bh0, acc0, 0, 0, 0);
            acc1 = __builtin_amdgcn_mfma_f32_16x16x32_f16(xhi, bh1, acc1, 0, 0, 0);
            acc0 = __builtin_amdgcn_mfma_f32_16x16x32_f16(xlo, bh0, acc0, 0, 0, 0);
            acc1 = __builtin_amdgcn_mfma_f32_16x16x32_f16(xlo, bh1, acc1, 0, 0, 0);
            acc0 = __builtin_amdgcn_mfma_f32_16x16x32_f16(xhi, bl0, acc0, 0, 0, 0);
            acc1 = __builtin_amdgcn_mfma_f32_16x16x32_f16(xhi, bl1, acc1, 0, 0, 0);
        }

        // ---- flag-hint spin: wave wv's 16 producers are (bg<<6)+(wv<<4)+r ----
        {
            const int* fp = flags + ((t & 1) * NWG + (bg << 6) + (wv << 4)
                                     + (lane & 15)) * FSTRIDE;
            int spins = 0;
            for (;;) {
                int f = __hip_atomic_load(fp, __ATOMIC_RELAXED,
                                          __HIP_MEMORY_SCOPE_AGENT);
                if (__all(f >= t)) break;
                if (++spins > 2048) break;      // hint only; tags are the truth
                __builtin_amdgcn_s_sleep(1);
            }
        }

        // lane's h base in BYTES: batch row = 4096 B, wave k = 1024 B, quad = 16 B
        const u64 hb = (u64)hrd + ((u64)(b0 + lm) << 12) + (wv << 10) + (quad << 4);

        // ---- one round of 16 coalesced coherent fragment loads ----
        u32x4 v[16];
        #pragma unroll
        for (int ks = 0; ks < 16; ks++) {
            asm volatile("global_load_dwordx4 %0, %1, off sc0 sc1"
                         : "=&v"(v[ks]) : "v"(hb + (u64)(ks * 64)));
        }
        asm volatile("s_waitcnt vmcnt(0)" ::: "memory");

        // ---- validate every 16-bit tag; rare masked retry (fabric skew) ----
        for (;;) {
            u32 bad = 0;
            #pragma unroll
            for (int ks = 0; ks < 16; ks++)
                #pragma unroll
                for (int e = 0; e < 4; e++)
                    bad |= (v[ks][e] & TAG32) ^ E32;
            if (__all(bad == 0)) break;
            if (bad) {                       // only stale lanes re-load
                __builtin_amdgcn_s_sleep(1);
                #pragma unroll
                for (int ks = 0; ks < 16; ks++) {
                    asm volatile("global_load_dwordx4 %0, %1, off sc0 sc1"
                                 : "=&v"(v[ks]) : "v"(hb + (u64)(ks * 64)));
                }
            }
            asm volatile("s_waitcnt vmcnt(0)" ::: "memory");
        }

        // ---- h_{t-1} @ W_res^T: LSB-clear -> A-fragment, 32 MFMAs ----
        {
            const f16* w0 = Wr + lm * WPAD + wv * 512 + quad * 8;
            const f16* w1 = Wr + (lm + 16) * WPAD + wv * 512 + quad * 8;
            #pragma unroll
            for (int ks = 0; ks < 16; ks++) {
                f16x8 af;
                #pragma unroll
                for (int e = 0; e < 4; e++)
                    ((u32*)&af)[e] = v[ks][e] & ~TAG32;   // clear tag (<=1 ulp)
                f16x8 bf0 = *(const f16x8*)(w0 + ks * 32);   // LDS ds_read_b128
                f16x8 bf1 = *(const f16x8*)(w1 + ks * 32);
                acc0 = __builtin_amdgcn_mfma_f32_16x16x32_f16(af, bf0, acc0, 0, 0, 0);
                acc1 = __builtin_amdgcn_mfma_f32_16x16x32_f16(af, bf1, acc1, 0, 0, 0);
            }
        }

        // ---- per-wave partials to LDS (C/D layout: col=lane&15, row=quad*4+reg) ----
        {
            float* pw = part + wv * (BATS * PPAD);
            #pragma unroll
            for (int r = 0; r < 4; r++) {
                int m = quad * 4 + r;
                pw[m * PPAD + lm]      = acc0[r];
                pw[m * PPAD + 16 + lm] = acc1[r];
            }
        }
        __syncthreads();

        // ---- reduce 4 waves + tanh + store ----
        if (t == T_ - 1) {
            // final step: fp32 to out, 2 per thread (m = tid>>4, n = (tid&15)*2)
            const int m = tid >> 4;
            const int n = (tid & 15) * 2;
            const int o = m * PPAD + n;
            float s0 = part[o]     + part[BATS * PPAD + o]     + part[2 * BATS * PPAD + o]
                     + part[3 * BATS * PPAD + o];
            float s1 = part[o + 1] + part[BATS * PPAD + o + 1] + part[2 * BATS * PPAD + o + 1]
                     + part[3 * BATS * PPAD + o + 1];
            float* op = out + (size_t)(b0 + m) * H_ + r0 + n;
            op[0] = tanhf(s0);
            op[1] = tanhf(s1);
        } else if (tid < 128) {
            // h store: one u64 = 4 tagged halves per thread (m = tid>>3, n0 = (tid&7)*4)
            const int m  = tid >> 3;
            const int n0 = (tid & 7) * 4;
            const u16 bit = (u16)(((t + 1) >> 1) & 1);
            union { u16 h[4]; u64 u; } pk;
            #pragma unroll
            for (int e = 0; e < 4; e++) {
                const int o = m * PPAD + n0 + e;
                float s = part[o] + part[BATS * PPAD + o] + part[2 * BATS * PPAD + o]
                        + part[3 * BATS * PPAD + o];
                union { f16 f; u16 u; } cv;
                cv.f = (f16)tanhf(s);
                pk.h[e] = (u16)((cv.u & 0xFFFEu) | bit);   // mantissa LSB = tag
            }
            // fire-and-forget write-through; validity is in-band
            __hip_atomic_store((u64*)(hwr + (size_t)(b0 + m) * H_ + r0 + n0),
                               pk.u, __ATOMIC_RELAXED, __HIP_MEMORY_SCOPE_AGENT);
        }

        // protect LDS partials from next step's writes; all h stores ISSUED
        __syncthreads();

        // ---- flag hint publish (after barrier => after all store issues) ----
        if (t < T_ - 1 && tid == 0) {
            __hip_atomic_store(flags + (((t + 1) & 1) * NWG + wg) * FSTRIDE,
                               t + 1, __ATOMIC_RELAXED, __HIP_MEMORY_SCOPE_AGENT);
        }
    }
}

extern "C" void kernel_launch(void* const* d_in, const int* in_sizes, int n_in,
                              void* d_out, int out_size, void* d_ws, size_t ws_size,
                              hipStream_t stream)
{
    (void)in_sizes; (void)n_in; (void)out_size; (void)ws_size;
    const float* x    = (const float*)d_in[0];
    const float* Win  = (const float*)d_in[1];
    const float* Wres = (const float*)d_in[2];
    float* out = (float*)d_out;

    u16* ht0 = (u16*)d_ws;                        // [64][2048] fp16, LSB = tag
    u16* ht1 = ht0 + (size_t)B_ * H_;
    int* flags = (int*)((char*)d_ws + (size_t)2 * B_ * H_ * sizeof(u16));

    // buffer0: 0x00 -> h_0 = 0, tag 0 fresh for t=0; buffer1: 0x01 -> stale
    // until real h_1; flags: 0 (step-0 spin passes: 0 >= 0).
    hipMemsetAsync(d_ws, 0x00, (size_t)B_ * H_ * sizeof(u16), stream);
    hipMemsetAsync((char*)d_ws + (size_t)B_ * H_ * sizeof(u16), 0x01,
                   (size_t)B_ * H_ * sizeof(u16), stream);
    hipMemsetAsync(flags, 0, (size_t)2 * NWG * FSTRIDE * sizeof(int), stream);

    hipFuncSetAttribute((const void*)esn_kernel,
                        hipFuncAttributeMaxDynamicSharedMemorySize, LDS_TOTAL);

    void* args[] = {(void*)&x, (void*)&Win, (void*)&Wres, (void*)&out,
                    (void*)&ht0, (void*)&ht1, (void*)&flags};
    hipLaunchCooperativeKernel((const void*)esn_kernel, dim3(NWG), dim3(256),
                               args, LDS_TOTAL, stream);
}

// Round 13
// 2590.979 us; speedup vs baseline: 1.9710x; 1.0053x over previous
//
#include <hip/hip_runtime.h>

// ESN recurrence on MI355X: h_t = tanh(x_t @ W_in^T + h_{t-1} @ W_res^T)
// B=64, T=512, I=128, H=2048. Persistent cooperative kernel, 256 WGs (1/CU).
// Logical WG (bg,j): batches [bg*16,+16), rows [j*32,+32).
// R13 = R12 (in-band 1-bit fp16-LSB tags = truth; flag hints = detection)
// + XCD-LOCAL h CACHING. Evidence R6-R12: step time ~ bytes through the
// L2-bypassing coherent path (~3.2 TB/s ceiling); h is read 64x amplified.
// Changes:
//  - block remap (assumes XCD = blockIdx&7; perf heuristic only): each XCD
//    hosts 32 same-bg WGs, so all WGs on an XCD read the SAME 64 KB of h.
//  - h loads are sc0-only (bypass L1, CACHED in XCD L2): first reader per
//    line refills fresh L3->L2, the rest hit L2 (34 TB/s aggregate).
//  - one leader WG per XCD (wg<8) runs an agent-acquire fence (buffer_inv)
//    each step inside its retry loop -> L2 can never serve data older than
//    h_{t-2}, whose tag bit mismatches (L3 is monotone: h_t or h_{t-2} only).
//  - retry escalation: after 8 stale rounds a lane reloads with sc0 sc1
//    (L2-bypass) -> unconditional progress even if the XCD mapping
//    assumption is false (degenerates to ~R12 behavior, still correct).

#define B_ 64
#define T_ 512
#define I_ 128
#define H_ 2048
#define NWG 256
#define ROWS 32          // output rows per WG
#define BATS 16          // batches per WG
#define WPAD 2056        // 2048 + 8 halves row pad
#define IPAD 136         // 128 + 8 halves row pad
#define PPAD 33          // partial row pad (break 32-bank stride)
#define FSTRIDE 16       // flag stride in dwords (64 B line per producer)

typedef _Float16 f16;
typedef f16 f16x8 __attribute__((ext_vector_type(8)));
typedef float f32x4 __attribute__((ext_vector_type(4)));
typedef unsigned long long u64;
typedef unsigned int u32;
typedef unsigned short u16;
typedef u32 u32x4 __attribute__((ext_vector_type(4)));

#define TAG32 0x00010001u            // mantissa-LSB mask, 2 halves per dword

// LDS layout (bytes):
//   Wres  : ROWS*WPAD*2           = 131584
//   Win_hi: ROWS*IPAD*2           =   8704
//   Win_lo: ROWS*IPAD*2           =   8704
//   part  : 4*BATS*PPAD*4         =   8448
#define LDS_WRES   0
#define LDS_WINHI  131584
#define LDS_WINLO  (131584 + 8704)
#define LDS_PART   (131584 + 17408)
#define LDS_TOTAL  (131584 + 17408 + 8448)

extern "C" __global__ __launch_bounds__(256, 1)
void esn_kernel(const float* __restrict__ x, const float* __restrict__ Win,
                const float* __restrict__ Wres, float* __restrict__ out,
                u16* ht0, u16* ht1, int* flags)
{
    extern __shared__ char lds[];
    f16*   Wr   = (f16*)(lds + LDS_WRES);    // [ROWS][WPAD]
    f16*   Whi  = (f16*)(lds + LDS_WINHI);   // [ROWS][IPAD]
    f16*   Wlo  = (f16*)(lds + LDS_WINLO);   // [ROWS][IPAD]
    float* part = (float*)(lds + LDS_PART);  // [4][BATS][PPAD]

    const int tid  = threadIdx.x;
    const int wg   = blockIdx.x;
    // XCD-aware remap (XCD = wg&7 assumed): bg's 64 WGs sit on XCDs {2bg,2bg+1}
    const int bg   = (wg & 7) >> 1;             // batch group 0..3
    const int j    = ((wg >> 3) << 1) | (wg & 1); // row group 0..63
    const int lid  = (bg << 6) | j;             // logical id (flag index)
    const bool leader = (wg < 8);               // one WG per XCD (under the map)
    const int r0   = j * ROWS;
    const int b0   = bg * BATS;
    const int wv   = tid >> 6;      // wave 0..3
    const int lane = tid & 63;
    const int lm   = lane & 15;     // A: m index / B: n index / C: col index
    const int quad = lane >> 4;     // 0..3

    // ---- one-time init: stage W_res slice (fp32 -> fp16) into LDS ----
    for (int idx = tid; idx < ROWS * (H_ / 4); idx += 256) {
        int r  = idx >> 9;          // 512 float4 per row
        int c4 = idx & 511;
        const float4 v = ((const float4*)(Wres + (size_t)(r0 + r) * H_))[c4];
        f16* dst = Wr + r * WPAD + c4 * 4;
        dst[0] = (f16)v.x; dst[1] = (f16)v.y; dst[2] = (f16)v.z; dst[3] = (f16)v.w;
    }
    // ---- W_in slice as fp16 hi + lo (precision split) ----
    for (int idx = tid; idx < ROWS * (I_ / 4); idx += 256) {
        int r  = idx >> 5;          // 32 float4 per row
        int c4 = idx & 31;
        const float4 v = ((const float4*)(Win + (size_t)(r0 + r) * I_))[c4];
        float vv[4] = {v.x, v.y, v.z, v.w};
        f16* dh = Whi + r * IPAD + c4 * 4;
        f16* dl = Wlo + r * IPAD + c4 * 4;
        #pragma unroll
        for (int q = 0; q < 4; q++) {
            f16 hi = (f16)vv[q];
            dh[q] = hi;
            dl[q] = (f16)(vv[q] - (float)hi);
        }
    }
    __syncthreads();

    for (int t = 0; t < T_; t++) {
        const u16* hrd = (t & 1) ? ht1 : ht0;   // fresh data carries bit (t>>1)&1
        u16*       hwr = (t & 1) ? ht0 : ht1;   // write h_{t+1}, bit ((t+1)>>1)&1
        const u32  E32 = ((t >> 1) & 1) ? TAG32 : 0u;

        f32x4 acc0 = {0.f, 0.f, 0.f, 0.f};
        f32x4 acc1 = {0.f, 0.f, 0.f, 0.f};

        // ---- x_t @ W_in^T with fp16 hi/lo split (before the wait) ----
        {
            const int kin = wv * 32 + quad * 8;
            const float* xp = x + ((size_t)(b0 + lm) * T_ + t) * I_ + kin;
            float xf[8];
            *(float4*)(xf)     = *(const float4*)(xp);
            *(float4*)(xf + 4) = *(const float4*)(xp + 4);
            f16x8 xhi, xlo;
            #pragma unroll
            for (int qq = 0; qq < 8; qq++) {
                f16 hi = (f16)xf[qq];
                xhi[qq] = hi;
                xlo[qq] = (f16)(xf[qq] - (float)hi);
            }
            f16x8 bh0 = *(const f16x8*)(Whi + lm * IPAD + kin);
            f16x8 bh1 = *(const f16x8*)(Whi + (lm + 16) * IPAD + kin);
            f16x8 bl0 = *(const f16x8*)(Wlo + lm * IPAD + kin);
            f16x8 bl1 = *(const f16x8*)(Wlo + (lm + 16) * IPAD + kin);
            acc0 = __builtin_amdgcn_mfma_f32_16x16x32_f16(xhi, bh0, acc0, 0, 0, 0);
            acc1 = __builtin_amdgcn_mfma_f32_16x16x32_f16(xhi, bh1, acc1, 0, 0, 0);
            acc0 = __builtin_amdgcn_mfma_f32_16x16x32_f16(xlo, bh0, acc0, 0, 0, 0);
            acc1 = __builtin_amdgcn_mfma_f32_16x16x32_f16(xlo, bh1, acc1, 0, 0, 0);
            acc0 = __builtin_amdgcn_mfma_f32_16x16x32_f16(xhi, bl0, acc0, 0, 0, 0);
            acc1 = __builtin_amdgcn_mfma_f32_16x16x32_f16(xhi, bl1, acc1, 0, 0, 0);
        }

        // ---- flag-hint spin: wave wv's 16 producers (logical) ----
        {
            const int* fp = flags + ((t & 1) * NWG + (bg << 6) + (wv << 4)
                                     + (lane & 15)) * FSTRIDE;
            int spins = 0;
            for (;;) {
                int f = __hip_atomic_load(fp, __ATOMIC_RELAXED,
                                          __HIP_MEMORY_SCOPE_AGENT);
                if (__all(f >= t)) break;
                if (++spins > 4096) break;      // hint only; tags are the truth
                __builtin_amdgcn_s_sleep(1);
            }
        }

        // leader refreshes this XCD's L2 view (buffer_inv) before loads
        if (leader) __builtin_amdgcn_fence(__ATOMIC_ACQUIRE, "agent");

        // lane's h base in BYTES: batch row = 4096 B, wave k = 1024 B, quad = 16 B
        const u64 hb = (u64)hrd + ((u64)(b0 + lm) << 12) + (wv << 10) + (quad << 4);

        // ---- 16 fragment loads, L2-cached (sc0: L1-bypass only) ----
        u32x4 v[16];
        #pragma unroll
        for (int ks = 0; ks < 16; ks++) {
            asm volatile("global_load_dwordx4 %0, %1, off sc0"
                         : "=&v"(v[ks]) : "v"(hb + (u64)(ks * 64)));
        }
        asm volatile("s_waitcnt vmcnt(0)" ::: "memory");

        // ---- validate tags; retry via L2; escalate to L2-bypass after 8 ----
        int rounds = 0;
        for (;;) {
            u32 bad = 0;
            #pragma unroll
            for (int ks = 0; ks < 16; ks++)
                #pragma unroll
                for (int e = 0; e < 4; e++)
                    bad |= (v[ks][e] & TAG32) ^ E32;
            if (__all(bad == 0)) break;
            ++rounds;
            if (leader) __builtin_amdgcn_fence(__ATOMIC_ACQUIRE, "agent");
            if (bad) {                       // only stale lanes re-load
                __builtin_amdgcn_s_sleep(1);
                if (rounds < 8) {
                    #pragma unroll
                    for (int ks = 0; ks < 16; ks++) {
                        asm volatile("global_load_dwordx4 %0, %1, off sc0"
                                     : "=&v"(v[ks]) : "v"(hb + (u64)(ks * 64)));
                    }
                } else {                     // safety valve: coherence point
                    #pragma unroll
                    for (int ks = 0; ks < 16; ks++) {
                        asm volatile("global_load_dwordx4 %0, %1, off sc0 sc1"
                                     : "=&v"(v[ks]) : "v"(hb + (u64)(ks * 64)));
                    }
                }
            }
            asm volatile("s_waitcnt vmcnt(0)" ::: "memory");
        }

        // ---- h_{t-1} @ W_res^T: LSB-clear -> A-fragment, 32 MFMAs ----
        {
            const f16* w0 = Wr + lm * WPAD + wv * 512 + quad * 8;
            const f16* w1 = Wr + (lm + 16) * WPAD + wv * 512 + quad * 8;
            #pragma unroll
            for (int ks = 0; ks < 16; ks++) {
                f16x8 af;
                #pragma unroll
                for (int e = 0; e < 4; e++)
                    ((u32*)&af)[e] = v[ks][e] & ~TAG32;   // clear tag (<=1 ulp)
                f16x8 bf0 = *(const f16x8*)(w0 + ks * 32);   // LDS ds_read_b128
                f16x8 bf1 = *(const f16x8*)(w1 + ks * 32);
                acc0 = __builtin_amdgcn_mfma_f32_16x16x32_f16(af, bf0, acc0, 0, 0, 0);
                acc1 = __builtin_amdgcn_mfma_f32_16x16x32_f16(af, bf1, acc1, 0, 0, 0);
            }
        }

        // ---- per-wave partials to LDS (C/D layout: col=lane&15, row=quad*4+reg) ----
        {
            float* pw = part + wv * (BATS * PPAD);
            #pragma unroll
            for (int r = 0; r < 4; r++) {
                int m = quad * 4 + r;
                pw[m * PPAD + lm]      = acc0[r];
                pw[m * PPAD + 16 + lm] = acc1[r];
            }
        }
        __syncthreads();

        // ---- reduce 4 waves + tanh + store ----
        if (t == T_ - 1) {
            // final step: fp32 to out, 2 per thread (m = tid>>4, n = (tid&15)*2)
            const int m = tid >> 4;
            const int n = (tid & 15) * 2;
            const int o = m * PPAD + n;
            float s0 = part[o]     + part[BATS * PPAD + o]     + part[2 * BATS * PPAD + o]
                     + part[3 * BATS * PPAD + o];
            float s1 = part[o + 1] + part[BATS * PPAD + o + 1] + part[2 * BATS * PPAD + o + 1]
                     + part[3 * BATS * PPAD + o + 1];
            float* op = out + (size_t)(b0 + m) * H_ + r0 + n;
            op[0] = tanhf(s0);
            op[1] = tanhf(s1);
        } else if (tid < 128) {
            // h store: one u64 = 4 tagged halves per thread (m = tid>>3, n0 = (tid&7)*4)
            const int m  = tid >> 3;
            const int n0 = (tid & 7) * 4;
            const u16 bit = (u16)(((t + 1) >> 1) & 1);
            union { u16 h[4]; u64 u; } pk;
            #pragma unroll
            for (int e = 0; e < 4; e++) {
                const int o = m * PPAD + n0 + e;
                float s = part[o] + part[BATS * PPAD + o] + part[2 * BATS * PPAD + o]
                        + part[3 * BATS * PPAD + o];
                union { f16 f; u16 u; } cv;
                cv.f = (f16)tanhf(s);
                pk.h[e] = (u16)((cv.u & 0xFFFEu) | bit);   // mantissa LSB = tag
            }
            // fire-and-forget write-through to L3; validity is in-band
            __hip_atomic_store((u64*)(hwr + (size_t)(b0 + m) * H_ + r0 + n0),
                               pk.u, __ATOMIC_RELAXED, __HIP_MEMORY_SCOPE_AGENT);
        }

        // protect LDS partials from next step's writes; all h stores ISSUED
        __syncthreads();

        // ---- flag hint publish (after barrier => after all store issues) ----
        if (t < T_ - 1 && tid == 0) {
            __hip_atomic_store(flags + (((t + 1) & 1) * NWG + lid) * FSTRIDE,
                               t + 1, __ATOMIC_RELAXED, __HIP_MEMORY_SCOPE_AGENT);
        }
    }
}

extern "C" void kernel_launch(void* const* d_in, const int* in_sizes, int n_in,
                              void* d_out, int out_size, void* d_ws, size_t ws_size,
                              hipStream_t stream)
{
    (void)in_sizes; (void)n_in; (void)out_size; (void)ws_size;
    const float* x    = (const float*)d_in[0];
    const float* Win  = (const float*)d_in[1];
    const float* Wres = (const float*)d_in[2];
    float* out = (float*)d_out;

    u16* ht0 = (u16*)d_ws;                        // [64][2048] fp16, LSB = tag
    u16* ht1 = ht0 + (size_t)B_ * H_;
    int* flags = (int*)((char*)d_ws + (size_t)2 * B_ * H_ * sizeof(u16));

    // buffer0: 0x00 -> h_0 = 0, tag 0 fresh for t=0; buffer1: 0x01 -> stale
    // until real h_1; flags: 0 (step-0 spin passes: 0 >= 0).
    hipMemsetAsync(d_ws, 0x00, (size_t)B_ * H_ * sizeof(u16), stream);
    hipMemsetAsync((char*)d_ws + (size_t)B_ * H_ * sizeof(u16), 0x01,
                   (size_t)B_ * H_ * sizeof(u16), stream);
    hipMemsetAsync(flags, 0, (size_t)2 * NWG * FSTRIDE * sizeof(int), stream);

    hipFuncSetAttribute((const void*)esn_kernel,
                        hipFuncAttributeMaxDynamicSharedMemorySize, LDS_TOTAL);

    void* args[] = {(void*)&x, (void*)&Win, (void*)&Wres, (void*)&out,
                    (void*)&ht0, (void*)&ht1, (void*)&flags};
    hipLaunchCooperativeKernel((const void*)esn_kernel, dim3(NWG), dim3(256),
                               args, LDS_TOTAL, stream);
}